// Round 8
// baseline (262.565 us; speedup 1.0000x reference)
//
#include <hip/hip_runtime.h>

// confidence_maps: (8,6,4,512,512) f32; warp_masks: (8,1,512,512) f32;
// gauss_kernel: (1,1,5,5) f32.
// Output: mask (48,1,512,512) f32 + rate scalar = 12,582,913 floats.
//
// Validated invariants (rounds 1-7, absmax 0.0):
//  - rate == 0.5 exactly; ego rows (l==0) all-ones, excluded from rate.
//  - max_c(sigmoid) == sigmoid(max_c).
//  - u16-key selection, +/-KAPPA=2 band, exact f64 resolve of band candidates.
//
// Round-8 (recombination; round-7 post-mortem: fusing the 256-bin hist back
// into compute without privatization re-introduced hot-bin LDS atomic
// serialization — smoothed field is concentrated, sigma~0.03 -> ~10% of
// pixels in a few bins; round 6's atomic-free compute + privatized hist pass
// was the fastest structure):
//  - compute: atomic-free separable f32 conv (round 6).
//  - hist1: separate streaming pass, 8-copy privatized bins (round 6).
//  - hist2: NOW also 8-copy privatized (sub-bins of b1 are equally hot).
//  - cand_eval: branchless clamped-load version (round 7), full blocks.
//  - rank_write: LDS staging + parallel cntAbove reduction (round 7).
//  - no hipMemsetAsync; meta zeroed in ego_fill (round 7).

#define NROWSEL 40
#define NPIX    262144
#define KSEL    131072
#define CAND_CAP 4096
#define KAPPA    2

// ---- workspace layout (bytes) ----
#define OFF_KEY  0ull                  // 40*262144 u16 = 20,971,520
#define OFF_H1   20971520ull           // 40*256 u32    =     40,960
#define OFF_H2   21012480ull           // 40*256 u32    =     40,960
#define OFF_ST   21053440ull           // 40*4 int      =        640
#define OFF_CC   21054080ull           // 40 u32        =        160
#define OFF_CI   21054240ull           // 40*4096 int   =    655,360
#define OFF_CK   21709600ull           // 40*4096 u16   =    327,680
#define OFF_CV   22037280ull           // 40*4096 f64   =  1,310,720
#define META_U32 20680                 // (H1+H2+ST+CC)/4 = 82,720 B

// fast f32 m = sigmoid(max_c conf) * warp  (hot path, approximate)
__device__ __forceinline__ float m_val_f32(const float* __restrict__ confr,
                                           const float* __restrict__ warpr,
                                           int gy, int gx) {
  if (gy < 0 || gy >= 512 || gx < 0 || gx >= 512) return 0.0f;
  int off = gy * 512 + gx;
  float x0 = confr[off];
  float x1 = confr[NPIX + off];
  float x2 = confr[2 * NPIX + off];
  float x3 = confr[3 * NPIX + off];
  float mx = fmaxf(fmaxf(x0, x1), fmaxf(x2, x3));
  float s = 1.0f / (1.0f + expf(-mx));
  return s * warpr[off];
}

// Fill the 8 ego rows (l==0) with 1.0 AND zero the selection metadata.
__global__ void ego_fill_kernel(float* __restrict__ out,
                                unsigned* __restrict__ meta) {
  int i = blockIdx.x * 256 + threadIdx.x;   // 524288 float4 units
  int b = i >> 16;
  int o4 = i & 65535;
  float4* p = (float4*)(out + (size_t)b * 6u * NPIX) + o4;
  *p = make_float4(1.f, 1.f, 1.f, 1.f);
  if (i < META_U32) meta[i] = 0u;
}

// Separable f32 conv: m halo (68x68) -> horizontal (68x64) -> vertical +
// u16 key store. Atomic-free.
__global__ __launch_bounds__(256) void compute_kernel(
    const float* __restrict__ conf, const float* __restrict__ warp,
    const float* __restrict__ gk, unsigned short* __restrict__ keys) {
  const int blk = blockIdx.x;        // 40 * 64
  const int j = blk >> 6;            // row 0..39
  const int tile = blk & 63;         // 8x8 tiles of 64x64
  const int ty0 = (tile >> 3) << 6;
  const int tx0 = (tile & 7) << 6;
  const int b = j / 5;
  const int l = j % 5 + 1;
  const int rowg = b * 6 + l;
  const float* confr = conf + (size_t)rowg * 4u * NPIX;
  const float* warpr = warp + (size_t)b * NPIX;

  __shared__ float mt[68][68];       // 18496 B
  __shared__ float ht[68][64];       // 17408 B
  __shared__ float wr[5], wc[5];
  const int tid = threadIdx.x;
  if (tid < 5) {
    wr[tid] = gk[10 + tid];               // c * a_dx  (middle row)
    wc[tid] = gk[tid * 5 + 2] / gk[12];   // a_dy      (middle col / center)
  }

  for (int i = tid; i < 68 * 68; i += 256) {
    int hy = i / 68, hx = i - hy * 68;
    mt[hy][hx] = m_val_f32(confr, warpr, ty0 + hy - 2, tx0 + hx - 2);
  }
  __syncthreads();

  for (int i = tid; i < 68 * 64; i += 256) {
    int hy = i >> 6, x = i & 63;
    float a = mt[hy][x] * wr[0];
    a = fmaf(wr[1], mt[hy][x + 1], a);
    a = fmaf(wr[2], mt[hy][x + 2], a);
    a = fmaf(wr[3], mt[hy][x + 3], a);
    a = fmaf(wr[4], mt[hy][x + 4], a);
    ht[hy][x] = a;
  }
  __syncthreads();

  const int txl = tid & 63;
  const int tyl = tid >> 6;          // 0..3
  unsigned short* keyrow = keys + (size_t)j * NPIX;
  for (int rr = 0; rr < 16; ++rr) {
    int yy = tyl + (rr << 2);        // 0..63
    float acc = ht[yy][txl] * wc[0];
    acc = fmaf(wc[1], ht[yy + 1][txl], acc);
    acc = fmaf(wc[2], ht[yy + 2][txl], acc);
    acc = fmaf(wc[3], ht[yy + 3][txl], acc);
    acc = fmaf(wc[4], ht[yy + 4][txl], acc);
    unsigned k = (unsigned)fminf(fmaxf(acc * 65536.0f, 0.0f), 65535.0f);
    keyrow[(ty0 + yy) * 512 + (tx0 + txl)] = (unsigned short)k;
  }
}

// Streaming coarse histogram (key high byte), 8-copy privatized LDS bins.
__global__ __launch_bounds__(256) void hist1_kernel(
    const unsigned short* __restrict__ keys, unsigned* __restrict__ hist1) {
  int blk = blockIdx.x;              // 40 * 32
  int j = blk >> 5, seg = blk & 31;  // 8192 keys per segment
  const uint4* kp = (const uint4*)(keys + (size_t)j * NPIX + seg * 8192);
  __shared__ unsigned lh[2048];      // 256 bins x 8 copies
  for (int i = threadIdx.x; i < 2048; i += 256) lh[i] = 0u;
  __syncthreads();
  int c = threadIdx.x & 7;
#pragma unroll
  for (int it = 0; it < 4; ++it) {
    uint4 k4 = kp[threadIdx.x + it * 256];
    unsigned w[4] = {k4.x, k4.y, k4.z, k4.w};
#pragma unroll
    for (int e = 0; e < 4; ++e) {
      atomicAdd(&lh[((w[e] & 0xFFFFu) >> 8) * 8 + c], 1u);
      atomicAdd(&lh[(w[e] >> 24) * 8 + c], 1u);
    }
  }
  __syncthreads();
  unsigned s = 0;
#pragma unroll
  for (int k = 0; k < 8; ++k) s += lh[threadIdx.x * 8 + k];
  if (s) atomicAdd(&hist1[j * 256 + threadIdx.x], s);
}

// Coarse: find high-byte bin b1 (descending); A1 = count strictly above.
__global__ void scan1_kernel(const unsigned* __restrict__ hist1,
                             int* __restrict__ st) {
  int j = blockIdx.x;
  const unsigned* h = hist1 + j * 256;
  __shared__ unsigned cs[256];
  int tid = threadIdx.x;
  cs[tid] = h[tid];
  __syncthreads();
  if (tid == 0) {
    unsigned cum = 0; int b1 = 255; unsigned A1 = 0;
    for (int c = 255; c >= 0; --c) {
      if (cum + cs[c] >= (unsigned)KSEL) { b1 = c; A1 = cum; break; }
      cum += cs[c];
    }
    st[j * 4 + 0] = b1;
    st[j * 4 + 1] = (int)A1;
  }
}

// Refine: histogram low byte for u16 keys whose high byte == b1.
// 8-copy privatized (sub-bins of the cutoff bin are hot).
__global__ __launch_bounds__(256) void hist2_kernel(
    const unsigned short* __restrict__ keys, const int* __restrict__ st,
    unsigned* __restrict__ hist2) {
  int blk = blockIdx.x;              // 40 * 32
  int j = blk >> 5, seg = blk & 31;
  unsigned b1 = (unsigned)st[j * 4 + 0];
  const uint4* kp = (const uint4*)(keys + (size_t)j * NPIX + seg * 8192);
  __shared__ unsigned lh[2048];      // 256 bins x 8 copies
  for (int i = threadIdx.x; i < 2048; i += 256) lh[i] = 0u;
  __syncthreads();
  int c = threadIdx.x & 7;
#pragma unroll
  for (int it = 0; it < 4; ++it) {
    uint4 k4 = kp[threadIdx.x + it * 256];
    unsigned w[4] = {k4.x, k4.y, k4.z, k4.w};
#pragma unroll
    for (int e = 0; e < 4; ++e) {
      unsigned lo = w[e] & 0xFFFFu, hi = w[e] >> 16;
      if ((lo >> 8) == b1) atomicAdd(&lh[(lo & 255u) * 8 + c], 1u);
      if ((hi >> 8) == b1) atomicAdd(&lh[(hi & 255u) * 8 + c], 1u);
    }
  }
  __syncthreads();
  unsigned s = 0;
#pragma unroll
  for (int k = 0; k < 8; ++k) s += lh[threadIdx.x * 8 + k];
  if (s) atomicAdd(&hist2[j * 256 + threadIdx.x], s);
}

// pstar = (b1<<8)|b2 (full u16 prefix); A2 = exact count of keys > pstar.
__global__ void scan2_kernel(const unsigned* __restrict__ hist2,
                             int* __restrict__ st) {
  int j = blockIdx.x;
  const unsigned* h = hist2 + j * 256;
  __shared__ unsigned cs[256];
  int tid = threadIdx.x;
  cs[tid] = h[tid];
  __syncthreads();
  if (tid == 0) {
    unsigned b1 = (unsigned)st[j * 4 + 0];
    unsigned A1 = (unsigned)st[j * 4 + 1];
    unsigned cum = A1; int b2 = 255; unsigned A2 = A1;
    for (int c = 255; c >= 0; --c) {
      if (cum + cs[c] >= (unsigned)KSEL) { b2 = c; A2 = cum; break; }
      cum += cs[c];
    }
    st[j * 4 + 2] = (int)((b1 << 8) | (unsigned)b2);
    st[j * 4 + 3] = (int)A2;
  }
}

// Decided bits: key > pstar+KAPPA -> 1, key < pstar-KAPPA -> 0.
// In-band keys -> gather (idx, key) for exact f64 resolution.
__global__ __launch_bounds__(256) void mask_gather_kernel(
    const unsigned short* __restrict__ keys, const int* __restrict__ st,
    float* __restrict__ out, unsigned* __restrict__ ccount,
    int* __restrict__ cidx, unsigned short* __restrict__ ckey) {
  int blk = blockIdx.x;              // 40 * 32
  int j = blk >> 5, seg = blk & 31;
  int b = j / 5, l = j % 5 + 1;
  int rowg = b * 6 + l;
  int pstar = st[j * 4 + 2];
  const uint4* kp = (const uint4*)(keys + (size_t)j * NPIX + seg * 8192);
  float4* o4 = (float4*)(out + (size_t)rowg * NPIX + seg * 8192);
#pragma unroll
  for (int it = 0; it < 4; ++it) {
    int q = threadIdx.x + it * 256;
    uint4 k4 = kp[q];                // 8 u16 keys
    unsigned w[4] = {k4.x, k4.y, k4.z, k4.w};
    float4 mv[2];
    float* mf = (float*)mv;
#pragma unroll
    for (int e = 0; e < 4; ++e) {
      int lo = (int)(w[e] & 0xFFFFu);
      int hi = (int)(w[e] >> 16);
      mf[e * 2]     = lo > pstar + KAPPA ? 1.f : 0.f;
      mf[e * 2 + 1] = hi > pstar + KAPPA ? 1.f : 0.f;
      if (lo >= pstar - KAPPA && lo <= pstar + KAPPA) {
        unsigned s = atomicAdd(&ccount[j], 1u);
        if (s < CAND_CAP) { cidx[j * CAND_CAP + s] = seg * 8192 + q * 8 + e * 2;
                            ckey[j * CAND_CAP + s] = (unsigned short)lo; }
      }
      if (hi >= pstar - KAPPA && hi <= pstar + KAPPA) {
        unsigned s = atomicAdd(&ccount[j], 1u);
        if (s < CAND_CAP) { cidx[j * CAND_CAP + s] = seg * 8192 + q * 8 + e * 2 + 1;
                            ckey[j * CAND_CAP + s] = (unsigned short)hi; }
      }
    }
    o4[q * 2] = mv[0];
    o4[q * 2 + 1] = mv[1];
  }
}

// Exact f64 recompute, branchless: 25 loads per dy-row issued unconditionally
// from clamped addresses, OOB handled by select. Deterministic f64 sequence;
// rank only needs accuracy (spacing ~4e-7 >> 1e-16), proven rounds 1-7.
__global__ __launch_bounds__(256) void cand_eval_kernel(
    const float* __restrict__ conf, const float* __restrict__ warp,
    const float* __restrict__ gk, const unsigned* __restrict__ ccount,
    const int* __restrict__ cidx, double* __restrict__ cval) {
  int blk = blockIdx.x;              // 40 * 16
  int j = blk >> 4;
  int i = (blk & 15) * 256 + (int)threadIdx.x;
  int C = (int)min(ccount[j], (unsigned)CAND_CAP);
  if (i >= C) return;
  int b = j / 5, l = j % 5 + 1;
  int rowg = b * 6 + l;
  const float* confr = conf + (size_t)rowg * 4u * NPIX;
  const float* warpr = warp + (size_t)b * NPIX;
  int idx = cidx[j * CAND_CAP + i];
  int y = idx >> 9, x = idx & 511;
  double acc = 0.0;
#pragma unroll
  for (int dy = 0; dy < 5; ++dy) {
    int cy = y + dy - 2;
    bool rin = (cy >= 0) && (cy < 512);
    int cyc = min(max(cy, 0), 511);
    float x0[5], x1[5], x2[5], x3[5], wv[5];
    bool cin[5];
#pragma unroll
    for (int dx = 0; dx < 5; ++dx) {
      int cx = x + dx - 2;
      cin[dx] = rin && (cx >= 0) && (cx < 512);
      int off = cyc * 512 + min(max(cx, 0), 511);
      x0[dx] = confr[off];
      x1[dx] = confr[NPIX + off];
      x2[dx] = confr[2 * NPIX + off];
      x3[dx] = confr[3 * NPIX + off];
      wv[dx] = warpr[off];
    }
#pragma unroll
    for (int dx = 0; dx < 5; ++dx) {
      float mx = fmaxf(fmaxf(x0[dx], x1[dx]), fmaxf(x2[dx], x3[dx]));
      double s = 1.0 / (1.0 + exp(-(double)mx));
      double m = cin[dx] ? s * (double)wv[dx] : 0.0;
      acc = fma((double)gk[dy * 5 + dx], m, acc);
    }
  }
  cval[j * CAND_CAP + i] = acc;
}

// Exact rank with (value desc, index asc) tie-break over LDS-resident band.
// R = K - A2 + #(cand key > pstar).
__global__ __launch_bounds__(256) void rank_write_kernel(
    const int* __restrict__ st, const unsigned* __restrict__ ccount,
    const int* __restrict__ cidx, const unsigned short* __restrict__ ckey,
    const double* __restrict__ cval, float* __restrict__ out) {
  int j = blockIdx.x;
  int b = j / 5, l = j % 5 + 1;
  int rowg = b * 6 + l;
  __shared__ double vs[CAND_CAP];    // 32 KB
  __shared__ int ids[CAND_CAP];      // 16 KB
  __shared__ unsigned red[256];
  int tid = threadIdx.x;
  int pstar = st[j * 4 + 2];
  int A2 = st[j * 4 + 3];
  int C = (int)min(ccount[j], (unsigned)CAND_CAP);
  unsigned cnt = 0;
  for (int i = tid; i < C; i += 256) {
    vs[i] = cval[j * CAND_CAP + i];
    ids[i] = cidx[j * CAND_CAP + i];
    cnt += (int)ckey[j * CAND_CAP + i] > pstar ? 1u : 0u;
  }
  red[tid] = cnt;
  __syncthreads();
  for (int s = 128; s > 0; s >>= 1) {
    if (tid < s) red[tid] += red[tid + s];
    __syncthreads();
  }
  int R = KSEL - A2 + (int)red[0];
  for (int i = tid; i < C; i += 256) {
    double vi = vs[i];
    int ii = ids[i];
    int rank = 0;
    for (int q = 0; q < C; ++q) {
      double vq = vs[q];
      rank += (vq > vi) || (vq == vi && ids[q] < ii) ? 1 : 0;
    }
    if (rank < R) out[(size_t)rowg * NPIX + ii] = 1.0f;
  }
  if (j == 0 && tid == 0) out[12582912] = 0.5f;  // rate == 0.5 exactly
}

extern "C" void kernel_launch(void* const* d_in, const int* in_sizes, int n_in,
                              void* d_out, int out_size, void* d_ws, size_t ws_size,
                              hipStream_t stream) {
  const float* conf = (const float*)d_in[0];
  const float* warp = (const float*)d_in[1];
  const float* gk   = (const float*)d_in[2];
  float* out = (float*)d_out;
  char* ws = (char*)d_ws;

  unsigned short* keys = (unsigned short*)(ws + OFF_KEY);
  unsigned* h1 = (unsigned*)(ws + OFF_H1);
  unsigned* h2 = (unsigned*)(ws + OFF_H2);
  int*      st = (int*)(ws + OFF_ST);
  unsigned* cc = (unsigned*)(ws + OFF_CC);
  int*      ci = (int*)(ws + OFF_CI);
  unsigned short* ck = (unsigned short*)(ws + OFF_CK);
  double*   cv = (double*)(ws + OFF_CV);

  // No hipMemsetAsync — meta zeroed by ego_fill_kernel (same stream, before
  // any consumer).
  ego_fill_kernel<<<2048, 256, 0, stream>>>(out, h1);
  compute_kernel<<<NROWSEL * 64, 256, 0, stream>>>(conf, warp, gk, keys);
  hist1_kernel<<<NROWSEL * 32, 256, 0, stream>>>(keys, h1);
  scan1_kernel<<<NROWSEL, 256, 0, stream>>>(h1, st);
  hist2_kernel<<<NROWSEL * 32, 256, 0, stream>>>(keys, st, h2);
  scan2_kernel<<<NROWSEL, 256, 0, stream>>>(h2, st);
  mask_gather_kernel<<<NROWSEL * 32, 256, 0, stream>>>(keys, st, out, cc, ci, ck);
  cand_eval_kernel<<<NROWSEL * 16, 256, 0, stream>>>(conf, warp, gk, cc, ci, cv);
  rank_write_kernel<<<NROWSEL, 256, 0, stream>>>(st, cc, ci, ck, cv, out);
}

// Round 9
// 217.601 us; speedup vs baseline: 1.2066x; 1.2066x over previous
//
#include <hip/hip_runtime.h>

// confidence_maps: (8,6,4,512,512) f32; warp_masks: (8,1,512,512) f32;
// gauss_kernel: (1,1,5,5) f32.
// Output: mask (48,1,512,512) f32 + rate scalar = 12,582,913 floats.
//
// Validated invariants (rounds 1-8, absmax 0.0 x8):
//  - rate == 0.5 exactly; ego rows (l==0) all-ones, excluded from rate.
//  - max_c(sigmoid) == sigmoid(max_c); separable gaussian (middle row/col
//    factorization) stays inside the +/-2-bin error band.
//  - u16-key selection: pstar/A2 from exact integer key counts; keys in
//    [pstar-2, pstar+2] resolved by exact-f64 recompute + (value desc,
//    index asc) rank; R = KSEL - A2 + #(cand key > pstar).
//
// Round-9 (structural: 9 kernels -> 5, boundaries 8 -> 4):
//  R8 null-result exonerated hist-fusion; cross-round accounting points at
//  per-kernel-boundary overhead as the dominant unexplained cost. Changes:
//  - hist1 fused into compute (4-copy privatized LDS bins) - pass deleted.
//  - scan1/scan2 kernels deleted; scans inlined (LDS + thread-0 serial)
//    into hist2 / mask_gather / resolve.
//  - cand_eval + rank_write fused into resolve_kernel (40 x 512, branchless
//    clamped-load f64 eval, LDS rank).

#define NROWSEL 40
#define NPIX    262144
#define KSEL    131072
#define CAND_CAP 2048
#define KAPPA    2

// ---- workspace layout (bytes) ----
#define OFF_KEY  0ull                  // 40*262144 u16 = 20,971,520
#define OFF_H1   20971520ull           // 40*256 u32    =     40,960
#define OFF_H2   21012480ull           // 40*256 u32    =     40,960
#define OFF_CC   21053440ull           // 40 u32        =        160
#define OFF_CI   21053600ull           // 40*2048 int   =    327,680
#define OFF_CK   21381280ull           // 40*2048 u16   =    163,840
#define META_U32 20520                 // (H1+H2+CC)/4 = 82,080 B

// fast f32 m = sigmoid(max_c conf) * warp  (hot path, approximate)
__device__ __forceinline__ float m_val_f32(const float* __restrict__ confr,
                                           const float* __restrict__ warpr,
                                           int gy, int gx) {
  if (gy < 0 || gy >= 512 || gx < 0 || gx >= 512) return 0.0f;
  int off = gy * 512 + gx;
  float x0 = confr[off];
  float x1 = confr[NPIX + off];
  float x2 = confr[2 * NPIX + off];
  float x3 = confr[3 * NPIX + off];
  float mx = fmaxf(fmaxf(x0, x1), fmaxf(x2, x3));
  float s = 1.0f / (1.0f + expf(-mx));
  return s * warpr[off];
}

// Descending scan over 256 LDS bins: first c (from 255) where cumulative
// (starting at cum0) crosses KSEL; above = count strictly above bin c.
__device__ __forceinline__ void scan256(const unsigned* __restrict__ cs,
                                        unsigned cum0, int& bsel,
                                        unsigned& above) {
  unsigned cum = cum0;
  bsel = 0; above = cum0;
  for (int c = 255; c >= 0; --c) {
    if (cum + cs[c] >= (unsigned)KSEL) { bsel = c; above = cum; break; }
    cum += cs[c];
  }
}

// K0: fill the 8 ego rows (l==0) with 1.0 AND zero selection metadata.
__global__ void ego_fill_kernel(float* __restrict__ out,
                                unsigned* __restrict__ meta) {
  int i = blockIdx.x * 256 + threadIdx.x;   // 524288 float4 units
  int b = i >> 16;
  int o4 = i & 65535;
  float4* p = (float4*)(out + (size_t)b * 6u * NPIX) + o4;
  *p = make_float4(1.f, 1.f, 1.f, 1.f);
  if (i < META_U32) meta[i] = 0u;
}

// K1: separable f32 conv (halo 68x68 -> horiz 68x64 -> vert) + u16 key store
// + fused 256-bin coarse histogram, 4-copy privatized.
__global__ __launch_bounds__(256) void compute_kernel(
    const float* __restrict__ conf, const float* __restrict__ warp,
    const float* __restrict__ gk, unsigned short* __restrict__ keys,
    unsigned* __restrict__ hist1) {
  const int blk = blockIdx.x;        // 40 * 64
  const int j = blk >> 6;            // row 0..39
  const int tile = blk & 63;         // 8x8 tiles of 64x64
  const int ty0 = (tile >> 3) << 6;
  const int tx0 = (tile & 7) << 6;
  const int b = j / 5;
  const int l = j % 5 + 1;
  const int rowg = b * 6 + l;
  const float* confr = conf + (size_t)rowg * 4u * NPIX;
  const float* warpr = warp + (size_t)b * NPIX;

  __shared__ float mt[68][68];       // 18496 B
  __shared__ float ht[68][64];       // 17408 B
  __shared__ unsigned lh[1024];      //  4096 B (256 bins x 4 copies) => ~40 KB
  __shared__ float wr[5], wc[5];
  const int tid = threadIdx.x;
  if (tid < 5) {
    wr[tid] = gk[10 + tid];               // c * a_dx  (middle row)
    wc[tid] = gk[tid * 5 + 2] / gk[12];   // a_dy      (middle col / center)
  }
  for (int i = tid; i < 1024; i += 256) lh[i] = 0u;

  for (int i = tid; i < 68 * 68; i += 256) {
    int hy = i / 68, hx = i - hy * 68;
    mt[hy][hx] = m_val_f32(confr, warpr, ty0 + hy - 2, tx0 + hx - 2);
  }
  __syncthreads();

  for (int i = tid; i < 68 * 64; i += 256) {
    int hy = i >> 6, x = i & 63;
    float a = mt[hy][x] * wr[0];
    a = fmaf(wr[1], mt[hy][x + 1], a);
    a = fmaf(wr[2], mt[hy][x + 2], a);
    a = fmaf(wr[3], mt[hy][x + 3], a);
    a = fmaf(wr[4], mt[hy][x + 4], a);
    ht[hy][x] = a;
  }
  __syncthreads();

  const int txl = tid & 63;
  const int tyl = tid >> 6;          // 0..3
  const int cpy = tid & 3;
  unsigned short* keyrow = keys + (size_t)j * NPIX;
  for (int rr = 0; rr < 16; ++rr) {
    int yy = tyl + (rr << 2);        // 0..63
    float acc = ht[yy][txl] * wc[0];
    acc = fmaf(wc[1], ht[yy + 1][txl], acc);
    acc = fmaf(wc[2], ht[yy + 2][txl], acc);
    acc = fmaf(wc[3], ht[yy + 3][txl], acc);
    acc = fmaf(wc[4], ht[yy + 4][txl], acc);
    unsigned k = (unsigned)fminf(fmaxf(acc * 65536.0f, 0.0f), 65535.0f);
    keyrow[(ty0 + yy) * 512 + (tx0 + txl)] = (unsigned short)k;
    atomicAdd(&lh[(k >> 8) * 4 + cpy], 1u);
  }
  __syncthreads();
  unsigned s = lh[tid * 4] + lh[tid * 4 + 1] + lh[tid * 4 + 2] + lh[tid * 4 + 3];
  if (s) atomicAdd(&hist1[j * 256 + tid], s);
}

// K2: refine histogram (low byte of keys whose high byte == b1), 8-copy
// privatized; b1 from INLINE scan of hist1.
__global__ __launch_bounds__(256) void hist2_kernel(
    const unsigned short* __restrict__ keys,
    const unsigned* __restrict__ hist1, unsigned* __restrict__ hist2) {
  int blk = blockIdx.x;              // 40 * 32
  int j = blk >> 5, seg = blk & 31;  // 8192 keys per segment
  __shared__ unsigned hs[256];
  __shared__ unsigned lh[2048];      // 256 bins x 8 copies
  __shared__ int s_b1;
  int tid = threadIdx.x;
  hs[tid] = hist1[j * 256 + tid];
  for (int i = tid; i < 2048; i += 256) lh[i] = 0u;
  __syncthreads();
  if (tid == 0) {
    int b1; unsigned A1;
    scan256(hs, 0u, b1, A1);
    s_b1 = b1;
  }
  __syncthreads();
  unsigned b1 = (unsigned)s_b1;
  const uint4* kp = (const uint4*)(keys + (size_t)j * NPIX + seg * 8192);
  int c = tid & 7;
#pragma unroll
  for (int it = 0; it < 4; ++it) {
    uint4 k4 = kp[tid + it * 256];
    unsigned w[4] = {k4.x, k4.y, k4.z, k4.w};
#pragma unroll
    for (int e = 0; e < 4; ++e) {
      unsigned lo = w[e] & 0xFFFFu, hi = w[e] >> 16;
      if ((lo >> 8) == b1) atomicAdd(&lh[(lo & 255u) * 8 + c], 1u);
      if ((hi >> 8) == b1) atomicAdd(&lh[(hi & 255u) * 8 + c], 1u);
    }
  }
  __syncthreads();
  unsigned s = 0;
#pragma unroll
  for (int k = 0; k < 8; ++k) s += lh[tid * 8 + k];
  if (s) atomicAdd(&hist2[j * 256 + tid], s);
}

// K3: INLINE scan1+scan2 -> pstar; write decided mask bits; gather band
// candidates (key in [pstar-KAPPA, pstar+KAPPA]).
__global__ __launch_bounds__(256) void mask_gather_kernel(
    const unsigned short* __restrict__ keys,
    const unsigned* __restrict__ hist1, const unsigned* __restrict__ hist2,
    float* __restrict__ out, unsigned* __restrict__ ccount,
    int* __restrict__ cidx, unsigned short* __restrict__ ckey) {
  int blk = blockIdx.x;              // 40 * 32
  int j = blk >> 5, seg = blk & 31;
  int b = j / 5, l = j % 5 + 1;
  int rowg = b * 6 + l;
  __shared__ unsigned hs[256];
  __shared__ int s_b1; __shared__ unsigned s_A1; __shared__ int s_pstar;
  int tid = threadIdx.x;
  hs[tid] = hist1[j * 256 + tid];
  __syncthreads();
  if (tid == 0) {
    int b1; unsigned A1;
    scan256(hs, 0u, b1, A1);
    s_b1 = b1; s_A1 = A1;
  }
  __syncthreads();
  hs[tid] = hist2[j * 256 + tid];
  __syncthreads();
  if (tid == 0) {
    int b2; unsigned A2;
    scan256(hs, s_A1, b2, A2);
    s_pstar = (s_b1 << 8) | b2;
  }
  __syncthreads();
  int pstar = s_pstar;

  const uint4* kp = (const uint4*)(keys + (size_t)j * NPIX + seg * 8192);
  float4* o4 = (float4*)(out + (size_t)rowg * NPIX + seg * 8192);
#pragma unroll
  for (int it = 0; it < 4; ++it) {
    int q = tid + it * 256;
    uint4 k4 = kp[q];                // 8 u16 keys
    unsigned w[4] = {k4.x, k4.y, k4.z, k4.w};
    float4 mv[2];
    float* mf = (float*)mv;
#pragma unroll
    for (int e = 0; e < 4; ++e) {
      int lo = (int)(w[e] & 0xFFFFu);
      int hi = (int)(w[e] >> 16);
      mf[e * 2]     = lo > pstar + KAPPA ? 1.f : 0.f;
      mf[e * 2 + 1] = hi > pstar + KAPPA ? 1.f : 0.f;
      if (lo >= pstar - KAPPA && lo <= pstar + KAPPA) {
        unsigned s = atomicAdd(&ccount[j], 1u);
        if (s < CAND_CAP) { cidx[j * CAND_CAP + s] = seg * 8192 + q * 8 + e * 2;
                            ckey[j * CAND_CAP + s] = (unsigned short)lo; }
      }
      if (hi >= pstar - KAPPA && hi <= pstar + KAPPA) {
        unsigned s = atomicAdd(&ccount[j], 1u);
        if (s < CAND_CAP) { cidx[j * CAND_CAP + s] = seg * 8192 + q * 8 + e * 2 + 1;
                            ckey[j * CAND_CAP + s] = (unsigned short)hi; }
      }
    }
    o4[q * 2] = mv[0];
    o4[q * 2 + 1] = mv[1];
  }
}

// K4: INLINE scans -> pstar, A2; branchless exact-f64 eval of candidates;
// exact rank (value desc, index asc); scatter top-R ones + rate.
__global__ __launch_bounds__(512) void resolve_kernel(
    const float* __restrict__ conf, const float* __restrict__ warp,
    const float* __restrict__ gk,
    const unsigned* __restrict__ hist1, const unsigned* __restrict__ hist2,
    const unsigned* __restrict__ ccount, const int* __restrict__ cidx,
    const unsigned short* __restrict__ ckey, float* __restrict__ out) {
  int j = blockIdx.x;                // 40
  int b = j / 5, l = j % 5 + 1;
  int rowg = b * 6 + l;
  const float* confr = conf + (size_t)rowg * 4u * NPIX;
  const float* warpr = warp + (size_t)b * NPIX;
  __shared__ unsigned hs[256];
  __shared__ double vs[CAND_CAP];    // 16 KB
  __shared__ int ids[CAND_CAP];      //  8 KB
  __shared__ unsigned red[512];      //  2 KB
  __shared__ int s_b1; __shared__ unsigned s_A1;
  __shared__ int s_pstar; __shared__ unsigned s_A2;
  int tid = threadIdx.x;
  if (tid < 256) hs[tid] = hist1[j * 256 + tid];
  __syncthreads();
  if (tid == 0) {
    int b1; unsigned A1;
    scan256(hs, 0u, b1, A1);
    s_b1 = b1; s_A1 = A1;
  }
  __syncthreads();
  if (tid < 256) hs[tid] = hist2[j * 256 + tid];
  __syncthreads();
  if (tid == 0) {
    int b2; unsigned A2;
    scan256(hs, s_A1, b2, A2);
    s_pstar = (s_b1 << 8) | b2; s_A2 = A2;
  }
  __syncthreads();
  int pstar = s_pstar;
  int A2 = (int)s_A2;
  int C = (int)min(ccount[j], (unsigned)CAND_CAP);

  // branchless exact f64 eval (clamped addresses + predicated select)
  unsigned cnt = 0;
  for (int i = tid; i < C; i += 512) {
    int idx = cidx[j * CAND_CAP + i];
    cnt += (int)ckey[j * CAND_CAP + i] > pstar ? 1u : 0u;
    int y = idx >> 9, x = idx & 511;
    double acc = 0.0;
#pragma unroll
    for (int dy = 0; dy < 5; ++dy) {
      int cy = y + dy - 2;
      bool rin = (cy >= 0) && (cy < 512);
      int cyc = min(max(cy, 0), 511);
      float x0[5], x1[5], x2[5], x3[5], wv[5];
      bool cin[5];
#pragma unroll
      for (int dx = 0; dx < 5; ++dx) {
        int cx = x + dx - 2;
        cin[dx] = rin && (cx >= 0) && (cx < 512);
        int off = cyc * 512 + min(max(cx, 0), 511);
        x0[dx] = confr[off];
        x1[dx] = confr[NPIX + off];
        x2[dx] = confr[2 * NPIX + off];
        x3[dx] = confr[3 * NPIX + off];
        wv[dx] = warpr[off];
      }
#pragma unroll
      for (int dx = 0; dx < 5; ++dx) {
        float mx = fmaxf(fmaxf(x0[dx], x1[dx]), fmaxf(x2[dx], x3[dx]));
        double s = 1.0 / (1.0 + exp(-(double)mx));
        double m = cin[dx] ? s * (double)wv[dx] : 0.0;
        acc = fma((double)gk[dy * 5 + dx], m, acc);
      }
    }
    vs[i] = acc;
    ids[i] = idx;
  }
  red[tid] = cnt;
  __syncthreads();
  for (int s = 256; s > 0; s >>= 1) {
    if (tid < s) red[tid] += red[tid + s];
    __syncthreads();
  }
  int R = KSEL - A2 + (int)red[0];

  for (int i = tid; i < C; i += 512) {
    double vi = vs[i];
    int ii = ids[i];
    int rank = 0;
    for (int q = 0; q < C; ++q) {
      double vq = vs[q];
      rank += (vq > vi) || (vq == vi && ids[q] < ii) ? 1 : 0;
    }
    if (rank < R) out[(size_t)rowg * NPIX + ii] = 1.0f;
  }
  if (j == 0 && tid == 0) out[12582912] = 0.5f;  // rate == 0.5 exactly
}

extern "C" void kernel_launch(void* const* d_in, const int* in_sizes, int n_in,
                              void* d_out, int out_size, void* d_ws, size_t ws_size,
                              hipStream_t stream) {
  const float* conf = (const float*)d_in[0];
  const float* warp = (const float*)d_in[1];
  const float* gk   = (const float*)d_in[2];
  float* out = (float*)d_out;
  char* ws = (char*)d_ws;

  unsigned short* keys = (unsigned short*)(ws + OFF_KEY);
  unsigned* h1 = (unsigned*)(ws + OFF_H1);
  unsigned* h2 = (unsigned*)(ws + OFF_H2);
  unsigned* cc = (unsigned*)(ws + OFF_CC);
  int*      ci = (int*)(ws + OFF_CI);
  unsigned short* ck = (unsigned short*)(ws + OFF_CK);

  // 5 kernels, 4 boundaries (was 9 / 8). No hipMemsetAsync.
  ego_fill_kernel<<<2048, 256, 0, stream>>>(out, h1);
  compute_kernel<<<NROWSEL * 64, 256, 0, stream>>>(conf, warp, gk, keys, h1);
  hist2_kernel<<<NROWSEL * 32, 256, 0, stream>>>(keys, h1, h2);
  mask_gather_kernel<<<NROWSEL * 32, 256, 0, stream>>>(keys, h1, h2, out, cc, ci, ck);
  resolve_kernel<<<NROWSEL, 512, 0, stream>>>(conf, warp, gk, h1, h2, cc, ci, ck, out);
}

// Round 10
// 149.653 us; speedup vs baseline: 1.7545x; 1.4540x over previous
//
#include <hip/hip_runtime.h>

// confidence_maps: (8,6,4,512,512) f32; warp_masks: (8,1,512,512) f32;
// gauss_kernel: (1,1,5,5) f32.
// Output: mask (48,1,512,512) f32 + rate scalar = 12,582,913 floats.
//
// Validated invariants (rounds 1-9, absmax 0.0 x9):
//  - rate == 0.5 exactly; ego rows (l==0) all-ones, excluded from rate.
//  - max_c(sigmoid) == sigmoid(max_c); separable gaussian factorization
//    (middle row/col) stays inside the error band.
//  - key selection: cutoff prefix + counts are EXACT integer counts of the
//    stored keys; band candidates resolved by exact f64 (branchy m_val,
//    25-tap gk) rank with (value desc, index asc); R = K - A2 + cntAbove.
//
// Round-10 (root-cause fix of the resolver):
//  - R6(branchy)=207 vs R7/R8(branchless)=261 isolates the branchless
//    cand_eval as a ~55us regression: 25-wide live arrays + f64 temps spill
//    to scratch (round-2 pathology). Instead of tuning the evaluator, shrink
//    its input: 20-bit linear keys (u32) -> band +/-3 bins of 2^-20 ->
//    C ~ 25 (was ~300 at u16). Resolve = R4-proven branchy f64, trivial.
//  - two-level selection on 1024+1024 bins (k>>10, k&1023), scans inlined
//    (256-chunk partials + thread-0 serial, ~1us), 5 kernels / 4 boundaries.
//  - error budget: eps(f32 sigmoid+separable conv) <~ 7e-7; kappa*q =
//    3*2^-20 = 2.9e-6 >= 4*eps -> decided bits provably match f64 reference.

#define NROWSEL 40
#define NPIX    262144
#define KSEL    131072
#define CAND_CAP 512
#define KAPPA    3
#define KSCALE   1048576.0f   // 2^20
#define KMAX     1048575.0f

// ---- workspace layout (bytes) ----
#define OFF_KEY  0ull                  // 40*262144 u32 = 41,943,040
#define OFF_H1   41943040ull           // 40*1024 u32   =    163,840
#define OFF_H2   42106880ull           // 40*1024 u32   =    163,840
#define OFF_ST   42270720ull           // 40*2 int      =        320
#define OFF_CC   42271040ull           // 40 u32        =        160
#define OFF_CI   42271200ull           // 40*512 int    =     81,920
#define OFF_CK   42353120ull           // 40*512 u32    =     81,920
#define META_U32 82040                 // (H1+H2+ST+CC)/4 = 328,160 B

// fast f32 m = sigmoid(max_c conf) * warp  (hot path, approximate)
__device__ __forceinline__ float m_val_f32(const float* __restrict__ confr,
                                           const float* __restrict__ warpr,
                                           int gy, int gx) {
  if (gy < 0 || gy >= 512 || gx < 0 || gx >= 512) return 0.0f;
  int off = gy * 512 + gx;
  float x0 = confr[off];
  float x1 = confr[NPIX + off];
  float x2 = confr[2 * NPIX + off];
  float x3 = confr[3 * NPIX + off];
  float mx = fmaxf(fmaxf(x0, x1), fmaxf(x2, x3));
  float s = 1.0f / (1.0f + expf(-mx));
  return s * warpr[off];
}

// exact f64 m (R1-R9 formula, proven absmax 0.0); used only in resolve.
__device__ __forceinline__ double m_val(const float* __restrict__ confr,
                                        const float* __restrict__ warpr,
                                        int gy, int gx) {
  if (gy < 0 || gy >= 512 || gx < 0 || gx >= 512) return 0.0;
  int off = gy * 512 + gx;
  float x0 = confr[off];
  float x1 = confr[NPIX + off];
  float x2 = confr[2 * NPIX + off];
  float x3 = confr[3 * NPIX + off];
  float mx = fmaxf(fmaxf(x0, x1), fmaxf(x2, x3));
  double s = 1.0 / (1.0 + exp(-(double)mx));
  return s * (double)warpr[off];
}

// Descending scan over 1024 LDS bins (hs), 256-chunk partials in red.
// Call with all 256 threads; result valid in *bsel/*above for tid==0 only.
__device__ __forceinline__ void scan1024(const unsigned* __restrict__ hs,
                                         unsigned* __restrict__ red,
                                         int tid, unsigned cum0,
                                         int* bsel, unsigned* above) {
  red[tid] = hs[tid * 4] + hs[tid * 4 + 1] + hs[tid * 4 + 2] + hs[tid * 4 + 3];
  __syncthreads();
  if (tid == 0) {
    unsigned cum = cum0;
    *bsel = 0; *above = cum0;
    for (int c = 255; c >= 0; --c) {
      if (cum + red[c] >= (unsigned)KSEL) {
        unsigned cc2 = cum;
        for (int k = 3; k >= 0; --k) {
          unsigned hv = hs[c * 4 + k];
          if (cc2 + hv >= (unsigned)KSEL) { *bsel = c * 4 + k; *above = cc2; break; }
          cc2 += hv;
        }
        break;
      }
      cum += red[c];
    }
  }
}

// K0: fill the 8 ego rows (l==0) with 1.0 AND zero selection metadata.
__global__ void ego_fill_kernel(float* __restrict__ out,
                                unsigned* __restrict__ meta) {
  int i = blockIdx.x * 256 + threadIdx.x;   // 524288 float4 units
  int b = i >> 16;
  int o4 = i & 65535;
  float4* p = (float4*)(out + (size_t)b * 6u * NPIX) + o4;
  *p = make_float4(1.f, 1.f, 1.f, 1.f);
  if (i < META_U32) meta[i] = 0u;
}

// K1: separable f32 conv (halo 68x68 -> horiz 68x64 -> vert) + u32 20-bit
// key store + fused 1024-bin coarse histogram (k>>10), 4-copy privatized.
__global__ __launch_bounds__(256) void compute_kernel(
    const float* __restrict__ conf, const float* __restrict__ warp,
    const float* __restrict__ gk, unsigned* __restrict__ keys,
    unsigned* __restrict__ hist1) {
  const int blk = blockIdx.x;        // 40 * 64
  const int j = blk >> 6;            // row 0..39
  const int tile = blk & 63;         // 8x8 tiles of 64x64
  const int ty0 = (tile >> 3) << 6;
  const int tx0 = (tile & 7) << 6;
  const int b = j / 5;
  const int l = j % 5 + 1;
  const int rowg = b * 6 + l;
  const float* confr = conf + (size_t)rowg * 4u * NPIX;
  const float* warpr = warp + (size_t)b * NPIX;

  __shared__ float mt[68][68];       // 18496 B
  __shared__ float ht[68][64];       // 17408 B
  __shared__ unsigned lh[4096];      // 16384 B (1024 bins x 4 copies)
  __shared__ float wr[5], wc[5];
  const int tid = threadIdx.x;
  if (tid < 5) {
    wr[tid] = gk[10 + tid];               // c * a_dx  (middle row)
    wc[tid] = gk[tid * 5 + 2] / gk[12];   // a_dy      (middle col / center)
  }
  for (int i = tid; i < 4096; i += 256) lh[i] = 0u;

  for (int i = tid; i < 68 * 68; i += 256) {
    int hy = i / 68, hx = i - hy * 68;
    mt[hy][hx] = m_val_f32(confr, warpr, ty0 + hy - 2, tx0 + hx - 2);
  }
  __syncthreads();

  for (int i = tid; i < 68 * 64; i += 256) {
    int hy = i >> 6, x = i & 63;
    float a = mt[hy][x] * wr[0];
    a = fmaf(wr[1], mt[hy][x + 1], a);
    a = fmaf(wr[2], mt[hy][x + 2], a);
    a = fmaf(wr[3], mt[hy][x + 3], a);
    a = fmaf(wr[4], mt[hy][x + 4], a);
    ht[hy][x] = a;
  }
  __syncthreads();

  const int txl = tid & 63;
  const int tyl = tid >> 6;          // 0..3
  const int cpy = tid & 3;
  unsigned* keyrow = keys + (size_t)j * NPIX;
  for (int rr = 0; rr < 16; ++rr) {
    int yy = tyl + (rr << 2);        // 0..63
    float acc = ht[yy][txl] * wc[0];
    acc = fmaf(wc[1], ht[yy + 1][txl], acc);
    acc = fmaf(wc[2], ht[yy + 2][txl], acc);
    acc = fmaf(wc[3], ht[yy + 3][txl], acc);
    acc = fmaf(wc[4], ht[yy + 4][txl], acc);
    unsigned k = (unsigned)fminf(fmaxf(acc * KSCALE, 0.0f), KMAX);
    keyrow[(ty0 + yy) * 512 + (tx0 + txl)] = k;
    atomicAdd(&lh[(k >> 10) * 4 + cpy], 1u);
  }
  __syncthreads();
  for (int i = tid; i < 1024; i += 256) {
    unsigned s = lh[i * 4] + lh[i * 4 + 1] + lh[i * 4 + 2] + lh[i * 4 + 3];
    if (s) atomicAdd(&hist1[j * 1024 + i], s);
  }
}

// K2: refine histogram (k&1023 for keys with k>>10 == b1), inline scan1,
// 4-copy privatized.
__global__ __launch_bounds__(256) void hist2_kernel(
    const unsigned* __restrict__ keys, const unsigned* __restrict__ hist1,
    unsigned* __restrict__ hist2) {
  int blk = blockIdx.x;              // 40 * 32
  int j = blk >> 5, seg = blk & 31;  // 8192 keys per segment
  __shared__ unsigned hs[1024];
  __shared__ unsigned red[256];
  __shared__ unsigned lh[4096];      // 1024 bins x 4 copies
  __shared__ int s_b1;
  int tid = threadIdx.x;
  for (int i = tid; i < 1024; i += 256) hs[i] = hist1[j * 1024 + i];
  for (int i = tid; i < 4096; i += 256) lh[i] = 0u;
  __syncthreads();
  int b1; unsigned A1;
  scan1024(hs, red, tid, 0u, &b1, &A1);
  if (tid == 0) s_b1 = b1;
  __syncthreads();
  unsigned ub1 = (unsigned)s_b1;
  const uint4* kp = (const uint4*)(keys + (size_t)j * NPIX + seg * 8192);
  int c = tid & 3;
#pragma unroll
  for (int it = 0; it < 8; ++it) {
    uint4 k4 = kp[tid + it * 256];
    if ((k4.x >> 10) == ub1) atomicAdd(&lh[(k4.x & 1023u) * 4 + c], 1u);
    if ((k4.y >> 10) == ub1) atomicAdd(&lh[(k4.y & 1023u) * 4 + c], 1u);
    if ((k4.z >> 10) == ub1) atomicAdd(&lh[(k4.z & 1023u) * 4 + c], 1u);
    if ((k4.w >> 10) == ub1) atomicAdd(&lh[(k4.w & 1023u) * 4 + c], 1u);
  }
  __syncthreads();
  for (int i = tid; i < 1024; i += 256) {
    unsigned s = lh[i * 4] + lh[i * 4 + 1] + lh[i * 4 + 2] + lh[i * 4 + 3];
    if (s) atomicAdd(&hist2[j * 1024 + i], s);
  }
}

// K3: inline scan1+scan2 -> pstar,A2 (seg 0 persists to st); write decided
// mask bits; gather band candidates (|k - pstar| <= KAPPA).
__global__ __launch_bounds__(256) void mask_gather_kernel(
    const unsigned* __restrict__ keys, const unsigned* __restrict__ hist1,
    const unsigned* __restrict__ hist2, float* __restrict__ out,
    int* __restrict__ st, unsigned* __restrict__ ccount,
    int* __restrict__ cidx, unsigned* __restrict__ ckey) {
  int blk = blockIdx.x;              // 40 * 32
  int j = blk >> 5, seg = blk & 31;
  int b = j / 5, l = j % 5 + 1;
  int rowg = b * 6 + l;
  __shared__ unsigned hs[1024];
  __shared__ unsigned red[256];
  __shared__ int s_pstar;
  int tid = threadIdx.x;
  for (int i = tid; i < 1024; i += 256) hs[i] = hist1[j * 1024 + i];
  __syncthreads();
  int b1; unsigned A1;
  scan1024(hs, red, tid, 0u, &b1, &A1);
  __syncthreads();                    // hs reload below
  for (int i = tid; i < 1024; i += 256) hs[i] = hist2[j * 1024 + i];
  __syncthreads();
  int b2; unsigned A2;
  scan1024(hs, red, tid, (tid == 0) ? A1 : 0u, &b2, &A2);
  if (tid == 0) {
    s_pstar = (b1 << 10) | b2;
    if (seg == 0) { st[j * 2] = s_pstar; st[j * 2 + 1] = (int)A2; }
  }
  __syncthreads();
  int pstar = s_pstar;

  const uint4* kp = (const uint4*)(keys + (size_t)j * NPIX + seg * 8192);
  float4* o4 = (float4*)(out + (size_t)rowg * NPIX + seg * 8192);
#pragma unroll
  for (int it = 0; it < 8; ++it) {
    int q = tid + it * 256;
    uint4 k4 = kp[q];
    unsigned w[4] = {k4.x, k4.y, k4.z, k4.w};
    float4 mv;
    float* mf = (float*)&mv;
#pragma unroll
    for (int e = 0; e < 4; ++e) {
      int k = (int)w[e];
      mf[e] = k > pstar + KAPPA ? 1.f : 0.f;
      if (k >= pstar - KAPPA && k <= pstar + KAPPA) {
        unsigned s = atomicAdd(&ccount[j], 1u);
        if (s < CAND_CAP) {
          cidx[j * CAND_CAP + s] = seg * 8192 + q * 4 + e;
          ckey[j * CAND_CAP + s] = (unsigned)k;
        }
      }
    }
    o4[q] = mv;
  }
}

// K4: exact f64 eval of the ~25 band candidates (branchy m_val, 25-tap gk,
// R4-proven), exact rank (value desc, index asc), scatter top-R ones + rate.
__global__ __launch_bounds__(256) void resolve_kernel(
    const float* __restrict__ conf, const float* __restrict__ warp,
    const float* __restrict__ gk, const int* __restrict__ st,
    const unsigned* __restrict__ ccount, const int* __restrict__ cidx,
    const unsigned* __restrict__ ckey, float* __restrict__ out) {
  int j = blockIdx.x;                // 40
  int b = j / 5, l = j % 5 + 1;
  int rowg = b * 6 + l;
  const float* confr = conf + (size_t)rowg * 4u * NPIX;
  const float* warpr = warp + (size_t)b * NPIX;
  __shared__ double vs[CAND_CAP];    // 4 KB
  __shared__ int ids[CAND_CAP];      // 2 KB
  __shared__ unsigned red[256];
  __shared__ double g[25];
  int tid = threadIdx.x;
  if (tid < 25) g[tid] = (double)gk[tid];
  int pstar = st[j * 2];
  int A2 = st[j * 2 + 1];
  int C = (int)min(ccount[j], (unsigned)CAND_CAP);
  __syncthreads();
  unsigned cnt = 0;
  for (int i = tid; i < C; i += 256) {
    int idx = cidx[j * CAND_CAP + i];
    cnt += (int)ckey[j * CAND_CAP + i] > pstar ? 1u : 0u;
    int y = idx >> 9, x = idx & 511;
    double acc = 0.0;
#pragma unroll
    for (int dy = 0; dy < 5; ++dy)
#pragma unroll
      for (int dx = 0; dx < 5; ++dx)
        acc = fma(g[dy * 5 + dx], m_val(confr, warpr, y + dy - 2, x + dx - 2), acc);
    vs[i] = acc;
    ids[i] = idx;
  }
  red[tid] = cnt;
  __syncthreads();
  for (int s = 128; s > 0; s >>= 1) {
    if (tid < s) red[tid] += red[tid + s];
    __syncthreads();
  }
  int R = KSEL - A2 + (int)red[0];
  for (int i = tid; i < C; i += 256) {
    double vi = vs[i];
    int ii = ids[i];
    int rank = 0;
    for (int q = 0; q < C; ++q) {
      double vq = vs[q];
      rank += (vq > vi) || (vq == vi && ids[q] < ii) ? 1 : 0;
    }
    if (rank < R) out[(size_t)rowg * NPIX + ii] = 1.0f;
  }
  if (j == 0 && tid == 0) out[12582912] = 0.5f;  // rate == 0.5 exactly
}

extern "C" void kernel_launch(void* const* d_in, const int* in_sizes, int n_in,
                              void* d_out, int out_size, void* d_ws, size_t ws_size,
                              hipStream_t stream) {
  const float* conf = (const float*)d_in[0];
  const float* warp = (const float*)d_in[1];
  const float* gk   = (const float*)d_in[2];
  float* out = (float*)d_out;
  char* ws = (char*)d_ws;

  unsigned* keys = (unsigned*)(ws + OFF_KEY);
  unsigned* h1   = (unsigned*)(ws + OFF_H1);
  unsigned* h2   = (unsigned*)(ws + OFF_H2);
  int*      st   = (int*)(ws + OFF_ST);
  unsigned* cc   = (unsigned*)(ws + OFF_CC);
  int*      ci   = (int*)(ws + OFF_CI);
  unsigned* ck   = (unsigned*)(ws + OFF_CK);

  // 5 kernels, 4 boundaries. No hipMemsetAsync.
  ego_fill_kernel<<<2048, 256, 0, stream>>>(out, h1);
  compute_kernel<<<NROWSEL * 64, 256, 0, stream>>>(conf, warp, gk, keys, h1);
  hist2_kernel<<<NROWSEL * 32, 256, 0, stream>>>(keys, h1, h2);
  mask_gather_kernel<<<NROWSEL * 32, 256, 0, stream>>>(keys, h1, h2, out, st, cc, ci, ck);
  resolve_kernel<<<NROWSEL, 256, 0, stream>>>(conf, warp, gk, st, cc, ci, ck, out);
}